// Round 1
// baseline (662.474 us; speedup 1.0000x reference)
//
#include <hip/hip_runtime.h>
#include <hip/hip_bf16.h>
#include <math.h>

// ---------------------------------------------------------------------------
// FeatureAttnNet fused implementation for MI355X (gfx950)
//
// Pipeline (all on `stream`):
//   0. memsetAsync zeros (Gram accums, colsums, cmd stats)
//   1. prep_weights : fp32 [Wkz|Wkh]->WK bf16 [2048,256], [Wvz|Wvh]->WV bf16
//   2. cmd_stats    : colsum(cmd)[4] + Gram(cmd)[4x4 upper] via atomics
//   3. gram_kernel  : G_f = feat^T feat, G_h = hid^T hid (bf16 MFMA, split-K,
//                     fp32 atomicAdd), + colsums of feat/hid
//   4. rowstats     : t_j = w_j^T G w_j, u_j = w_j . colsum  (j = 0..2047)
//   5. finalize     : per-d BN constants -> Wq2[d][c] = c1_d*Wq[d][c], c0[d]
//   6. fused_attn   : per 256-row tile: per f in 0..31:
//                       K-tile GEMM (bf16 MFMA) -> scores -> online softmax
//                       V-tile GEMM -> weighted accumulate -> out [B,64] fp32
// Key identity: BN(K) is affine per-d; the additive part is constant over f
// and cancels in softmax, so scores = sum_d q'[b,d]*K[b,d,f] with
// q'[b,d] = c1_d*Q[b,d] + c0_d.
// ---------------------------------------------------------------------------

typedef float  f32x4  __attribute__((ext_vector_type(4)));
typedef __bf16 bf16x4 __attribute__((ext_vector_type(4)));
typedef __bf16 bf16x8 __attribute__((ext_vector_type(8)));

#define MFMA16(A, B, C) __builtin_amdgcn_mfma_f32_16x16x32_bf16((A), (B), (C), 0, 0, 0)

#define EPSV 1e-5f

// ---- workspace layout (bytes) ----
#define WS_WK    0x000000u   // 2048*256 bf16 = 1 MiB   [Wkz;Wkh]
#define WS_WV    0x100000u   // 1 MiB                   [Wvz;Wvh]
#define WS_G     0x200000u   // 2*256*256 f32 = 512 KiB (zeroed)
#define WS_CS    0x280000u   // 2*256 f32 colsums        (zeroed)
#define WS_CMD   0x280800u   // 14 f32 cmd stats         (zeroed)
#define WS_T     0x281000u   // 2048 f32  t_j
#define WS_U     0x283000u   // 2048 f32  u_j
#define WS_WQ2   0x285000u   // 256 f32   c1_d*Wq[d][c]
#define WS_C0    0x285400u   // 64 f32    c0_d
#define WS_ZERO_BASE WS_G
#define WS_ZERO_SIZE (WS_CMD + 64u - WS_G)

// ---------------------------------------------------------------------------
__global__ void prep_weights(const float* __restrict__ Wkz, const float* __restrict__ Wkh,
                             const float* __restrict__ Wvz, const float* __restrict__ Wvh,
                             __bf16* __restrict__ WK, __bf16* __restrict__ WV)
{
    int t = blockIdx.x * 256 + threadIdx.x;     // 0..131071
    int e = t * 4;                              // element offset in [0, 524288)
    const float* srcK = (e < 262144) ? (Wkz + e) : (Wkh + (e - 262144));
    const float* srcV = (e < 262144) ? (Wvz + e) : (Wvh + (e - 262144));
    float4 a = *(const float4*)srcK;
    float4 b = *(const float4*)srcV;
    bf16x4 va = { (__bf16)a.x, (__bf16)a.y, (__bf16)a.z, (__bf16)a.w };
    bf16x4 vb = { (__bf16)b.x, (__bf16)b.y, (__bf16)b.z, (__bf16)b.w };
    *(bf16x4*)(WK + e) = va;
    *(bf16x4*)(WV + e) = vb;
}

// ---------------------------------------------------------------------------
__global__ void cmd_stats(const float4* __restrict__ cmd, float* __restrict__ out14)
{
    int g = blockIdx.x * 256 + threadIdx.x;     // one row per thread, B=65536
    float4 c = cmd[g];
    float v[14] = { c.x, c.y, c.z, c.w,
                    c.x*c.x, c.x*c.y, c.x*c.z, c.x*c.w,
                    c.y*c.y, c.y*c.z, c.y*c.w,
                    c.z*c.z, c.z*c.w, c.w*c.w };
#pragma unroll
    for (int k = 0; k < 14; ++k) {
        float s = v[k];
#pragma unroll
        for (int off = 32; off; off >>= 1) s += __shfl_xor(s, off);
        if ((threadIdx.x & 63) == 0) atomicAdd(&out14[k], s);
    }
}

// ---------------------------------------------------------------------------
// G = X^T X per matrix, via 16x16x32 bf16 MFMA. 256 blocks: 2 matrices x 128
// k-chunks (512 rows). Each block: full 256x256 partial, atomicAdd to G.
__global__ __launch_bounds__(512, 2) void gram_kernel(const float* __restrict__ feat,
        const float* __restrict__ hid, float* __restrict__ G, float* __restrict__ CS)
{
    __shared__ __bf16 T[256 * 40];   // [col i][k 0..31], stride 40 (pad: 2-way banks, 16B aligned)
    const int tid  = threadIdx.x;
    const int blk  = blockIdx.x;
    const int mat  = blk >> 7;
    const int chunk = blk & 127;
    const float* X = mat ? hid : feat;
    float* Gm = G + mat * 65536;
    float* cs = CS + mat * 256;
    const int k0   = chunk * 512;
    const int wid  = tid >> 6, lane = tid & 63, quad = lane >> 4, l15 = lane & 15;
    const int c    = tid & 255;      // this thread's column (fixed)
    const int t8   = tid >> 8;       // 0 or 1

    f32x4 acc[2][16];
#pragma unroll
    for (int mt = 0; mt < 2; ++mt)
#pragma unroll
        for (int nt = 0; nt < 16; ++nt) acc[mt][nt] = (f32x4){0.f, 0.f, 0.f, 0.f};

    float clsum = 0.f;
    for (int it = 0; it < 16; ++it) {
        __syncthreads();
        const int kb = k0 + it * 32;
#pragma unroll
        for (int i = 0; i < 16; ++i) {
            int k = t8 + 2 * i;
            float x = X[(size_t)(kb + k) * 256 + c];
            clsum += x;
            T[c * 40 + k] = (__bf16)x;
        }
        __syncthreads();
        bf16x8 a0 = *(const bf16x8*)&T[(wid * 32 +      l15) * 40 + quad * 8];
        bf16x8 a1 = *(const bf16x8*)&T[(wid * 32 + 16 + l15) * 40 + quad * 8];
#pragma unroll
        for (int nt = 0; nt < 16; ++nt) {
            bf16x8 b = *(const bf16x8*)&T[(nt * 16 + l15) * 40 + quad * 8];
            acc[0][nt] = MFMA16(a0, b, acc[0][nt]);
            acc[1][nt] = MFMA16(a1, b, acc[1][nt]);
        }
    }
    atomicAdd(&cs[c], clsum);
#pragma unroll
    for (int mt = 0; mt < 2; ++mt)
#pragma unroll
        for (int nt = 0; nt < 16; ++nt)
#pragma unroll
            for (int r = 0; r < 4; ++r) {
                int gi = wid * 32 + mt * 16 + quad * 4 + r;   // C/D: row = quad*4+reg
                int gj = nt * 16 + l15;                        //      col = lane&15
                atomicAdd(&Gm[gi * 256 + gj], acc[mt][nt][r]);
            }
}

// ---------------------------------------------------------------------------
// t_j = w_j^T G w_j ; u_j = w_j . colsum.  One block (256 thr) per j.
__global__ void rowstats(const float* __restrict__ Wkz, const float* __restrict__ Wkh,
        const float* __restrict__ G, const float* __restrict__ CS,
        float* __restrict__ Tout, float* __restrict__ Uout)
{
    const int j   = blockIdx.x;       // 0..2047
    const int mat = j >> 10;
    const float* w  = (mat ? Wkh : Wkz) + (size_t)(j & 1023) * 256;
    const float* Gm = G + mat * 65536;
    const float* cs = CS + mat * 256;
    __shared__ float wl[256];
    __shared__ float red[8];
    const int tid = threadIdx.x;
    wl[tid] = w[tid];
    __syncthreads();
    float inner = 0.f;
    for (int r = 0; r < 256; ++r) inner = fmaf(wl[r], Gm[r * 256 + tid], inner);
    float p  = wl[tid] * inner;
    float uu = wl[tid] * cs[tid];
#pragma unroll
    for (int off = 32; off; off >>= 1) { p += __shfl_xor(p, off); uu += __shfl_xor(uu, off); }
    int wid = tid >> 6;
    if ((tid & 63) == 0) { red[wid * 2] = p; red[wid * 2 + 1] = uu; }
    __syncthreads();
    if (tid == 0) {
        Tout[j] = red[0] + red[2] + red[4] + red[6];
        Uout[j] = red[1] + red[3] + red[5] + red[7];
    }
}

// ---------------------------------------------------------------------------
__global__ void finalize_kernel(const float* __restrict__ Wq,
        const float* __restrict__ gQ, const float* __restrict__ bQ,
        const float* __restrict__ gK, const float* __restrict__ bK,
        const float* __restrict__ cmd14, const float* __restrict__ T,
        const float* __restrict__ U, float* __restrict__ Wq2, float* __restrict__ C0)
{
    const int d = threadIdx.x;        // 0..63
    float s4[4] = { cmd14[0], cmd14[1], cmd14[2], cmd14[3] };
    float gc[4][4];
    gc[0][0] = cmd14[4];
    gc[0][1] = gc[1][0] = cmd14[5];
    gc[0][2] = gc[2][0] = cmd14[6];
    gc[0][3] = gc[3][0] = cmd14[7];
    gc[1][1] = cmd14[8];
    gc[1][2] = gc[2][1] = cmd14[9];
    gc[1][3] = gc[3][1] = cmd14[10];
    gc[2][2] = cmd14[11];
    gc[2][3] = gc[3][2] = cmd14[12];
    gc[3][3] = cmd14[13];
    float wq[4];
#pragma unroll
    for (int c = 0; c < 4; ++c) wq[c] = Wq[d * 4 + c];
    const float invB = 1.0f / 65536.0f;
    float mQ = (wq[0]*s4[0] + wq[1]*s4[1] + wq[2]*s4[2] + wq[3]*s4[3]) * invB;
    float eq2 = 0.f;
#pragma unroll
    for (int c = 0; c < 4; ++c)
#pragma unroll
        for (int c2 = 0; c2 < 4; ++c2) eq2 += wq[c] * wq[c2] * gc[c][c2];
    eq2 *= invB;
    float vQ  = eq2 - mQ * mQ;
    float aQ  = gQ[d] / sqrtf(vQ + EPSV);
    float bQv = bQ[d] - mQ * aQ;
    float S2 = 0.f, S1 = 0.f;
#pragma unroll
    for (int f = 0; f < 32; ++f) { S2 += T[f * 64 + d]; S1 += U[f * 64 + d]; }
    const float invBF = 1.0f / (65536.0f * 32.0f);
    float e2 = S2 * invBF, mK = S1 * invBF;
    float vK = e2 - mK * mK;
    float aK = gK[d] / sqrtf(vK + EPSV);
    float c1 = aQ * aK * 0.125f;      // 1/sqrt(64) folded in
    C0[d] = bQv * aK * 0.125f;
#pragma unroll
    for (int c = 0; c < 4; ++c) Wq2[d * 4 + c] = c1 * wq[c];
}

// ---------------------------------------------------------------------------
// fused attention helpers
__device__ __forceinline__ void stage_b(__bf16* __restrict__ Bs,
        const __bf16* __restrict__ src, int tid)
{
    __syncthreads();
#pragma unroll
    for (int s = 0; s < 4; ++s) {
        int cc = tid + s * 512;               // 0..2047 chunks of 8
        int n = cc >> 5, c8 = cc & 31;
        bf16x8 v = *(const bf16x8*)(src + n * 256 + c8 * 8);
        *(bf16x8*)&Bs[(n << 8) + ((c8 ^ (n & 7)) << 3)] = v;
    }
    __syncthreads();
}

__device__ __forceinline__ void gemm_tile(const __bf16* __restrict__ Bs,
        const bf16x8 (&areg)[2][8], int l15, int quad, int swz, f32x4 (&acc)[2][4])
{
#pragma unroll
    for (int mt = 0; mt < 2; ++mt)
#pragma unroll
        for (int nt = 0; nt < 4; ++nt) acc[mt][nt] = (f32x4){0.f, 0.f, 0.f, 0.f};
#pragma unroll
    for (int ks = 0; ks < 8; ++ks) {
        const int koff = ((((ks << 2) + quad) ^ swz) << 3) + (l15 << 8);
        bf16x8 b0 = *(const bf16x8*)&Bs[koff];
        bf16x8 b1 = *(const bf16x8*)&Bs[koff + (1 << 12)];
        bf16x8 b2 = *(const bf16x8*)&Bs[koff + (2 << 12)];
        bf16x8 b3 = *(const bf16x8*)&Bs[koff + (3 << 12)];
        acc[0][0] = MFMA16(areg[0][ks], b0, acc[0][0]);
        acc[0][1] = MFMA16(areg[0][ks], b1, acc[0][1]);
        acc[0][2] = MFMA16(areg[0][ks], b2, acc[0][2]);
        acc[0][3] = MFMA16(areg[0][ks], b3, acc[0][3]);
        acc[1][0] = MFMA16(areg[1][ks], b0, acc[1][0]);
        acc[1][1] = MFMA16(areg[1][ks], b1, acc[1][1]);
        acc[1][2] = MFMA16(areg[1][ks], b2, acc[1][2]);
        acc[1][3] = MFMA16(areg[1][ks], b3, acc[1][3]);
    }
}

// 256 blocks x 512 threads; block handles 256 batch rows; online softmax.
__global__ __launch_bounds__(512, 2) void fused_attn(
        const float* __restrict__ feat, const float* __restrict__ hid,
        const float4* __restrict__ cmd, const __bf16* __restrict__ WK,
        const __bf16* __restrict__ WV, const float4* __restrict__ Wq2,
        const float* __restrict__ C0, float* __restrict__ out)
{
    __shared__ __bf16 Xs[65536];   // 256 rows x 256 k, xor-swizzled, 128 KiB
    __shared__ __bf16 Bs[16384];   // 64 rows x 256 k, xor-swizzled, 32 KiB
    const int tid  = threadIdx.x;
    const int wid  = tid >> 6, lane = tid & 63, quad = lane >> 4, l15 = lane & 15;
    const int swz  = l15 & 7;
    const int b0   = blockIdx.x << 8;
    const int rowbase = wid << 5;  // wave handles 32 rows

    // q'[row][d] for this lane's (mt,r) rows x (nt) cols
    float qp[2][4][4];
    {
        float  c0r[4];
        float4 wqr[4];
#pragma unroll
        for (int nt = 0; nt < 4; ++nt) {
            c0r[nt] = C0[l15 + (nt << 4)];
            wqr[nt] = Wq2[l15 + (nt << 4)];
        }
#pragma unroll
        for (int mt = 0; mt < 2; ++mt)
#pragma unroll
            for (int r = 0; r < 4; ++r) {
                float4 cm = cmd[b0 + rowbase + (mt << 4) + (quad << 2) + r];
#pragma unroll
                for (int nt = 0; nt < 4; ++nt)
                    qp[mt][r][nt] = c0r[nt] + cm.x * wqr[nt].x + cm.y * wqr[nt].y
                                            + cm.z * wqr[nt].z + cm.w * wqr[nt].w;
            }
    }

    float m_i[2][4], l_i[2][4];
    f32x4 s_acc[2][4];
#pragma unroll
    for (int mt = 0; mt < 2; ++mt) {
#pragma unroll
        for (int r = 0; r < 4; ++r) { m_i[mt][r] = -1e30f; l_i[mt][r] = 0.f; }
#pragma unroll
        for (int nt = 0; nt < 4; ++nt) s_acc[mt][nt] = (f32x4){0.f, 0.f, 0.f, 0.f};
    }

    for (int half = 0; half < 2; ++half) {
        const float* X = half ? hid : feat;
        __syncthreads();
        {   // stage X half-tile: 256x256 fp32 -> bf16 swizzled LDS
            const int c8 = tid & 31;
            const int rb = tid >> 5;
#pragma unroll
            for (int i = 0; i < 16; ++i) {
                int row = rb + (i << 4);
                const float* src = X + ((size_t)(b0 + row) << 8) + (c8 << 3);
                float4 u0 = *(const float4*)src;
                float4 u1 = *(const float4*)(src + 4);
                bf16x8 v = { (__bf16)u0.x, (__bf16)u0.y, (__bf16)u0.z, (__bf16)u0.w,
                             (__bf16)u1.x, (__bf16)u1.y, (__bf16)u1.z, (__bf16)u1.w };
                *(bf16x8*)&Xs[(row << 8) + ((c8 ^ (row & 7)) << 3)] = v;
            }
        }
        __syncthreads();
        // A fragments in registers: reused across all 16 f's (and K+V GEMMs)
        bf16x8 areg[2][8];
#pragma unroll
        for (int mt = 0; mt < 2; ++mt)
#pragma unroll
            for (int ks = 0; ks < 8; ++ks)
                areg[mt][ks] = *(const bf16x8*)
                    &Xs[((rowbase + (mt << 4) + l15) << 8) + ((((ks << 2) + quad) ^ swz) << 3)];

        for (int fl = 0; fl < 16; ++fl) {
            const int f = (half << 4) + fl;
            f32x4 acc[2][4];
            // ---- K tile: scores ----
            stage_b(Bs, WK + ((size_t)f << 14), tid);
            gemm_tile(Bs, areg, l15, quad, swz, acc);
            float wgt[2][4];
#pragma unroll
            for (int mt = 0; mt < 2; ++mt)
#pragma unroll
                for (int r = 0; r < 4; ++r) {
                    float p = acc[mt][0][r] * qp[mt][r][0] + acc[mt][1][r] * qp[mt][r][1]
                            + acc[mt][2][r] * qp[mt][r][2] + acc[mt][3][r] * qp[mt][r][3];
                    p += __shfl_xor(p, 1);
                    p += __shfl_xor(p, 2);
                    p += __shfl_xor(p, 4);
                    p += __shfl_xor(p, 8);   // sum over 16 lanes (all 64 d)
                    float mo = m_i[mt][r];
                    float mn = fmaxf(mo, p);
                    float cc = __expf(mo - mn);
                    float wv = __expf(p - mn);
                    l_i[mt][r] = l_i[mt][r] * cc + wv;
                    m_i[mt][r] = mn;
                    wgt[mt][r] = wv;
                    s_acc[mt][0][r] *= cc;
                    s_acc[mt][1][r] *= cc;
                    s_acc[mt][2][r] *= cc;
                    s_acc[mt][3][r] *= cc;
                }
            // ---- V tile: weighted accumulate ----
            stage_b(Bs, WV + ((size_t)f << 14), tid);
            gemm_tile(Bs, areg, l15, quad, swz, acc);
#pragma unroll
            for (int mt = 0; mt < 2; ++mt)
#pragma unroll
                for (int nt = 0; nt < 4; ++nt)
#pragma unroll
                    for (int r = 0; r < 4; ++r)
                        s_acc[mt][nt][r] += wgt[mt][r] * acc[mt][nt][r];
        }
    }

    // epilogue: out[b,d] = s_acc / l
#pragma unroll
    for (int mt = 0; mt < 2; ++mt)
#pragma unroll
        for (int r = 0; r < 4; ++r) {
            float inv = 1.0f / l_i[mt][r];
            size_t row = (size_t)(b0 + rowbase + (mt << 4) + (quad << 2) + r);
#pragma unroll
            for (int nt = 0; nt < 4; ++nt)
                out[(row << 6) + l15 + (nt << 4)] = s_acc[mt][nt][r] * inv;
        }
}

// ---------------------------------------------------------------------------
extern "C" void kernel_launch(void* const* d_in, const int* in_sizes, int n_in,
                              void* d_out, int out_size, void* d_ws, size_t ws_size,
                              hipStream_t stream)
{
    (void)in_sizes; (void)n_in; (void)out_size; (void)ws_size;
    const float* feature = (const float*)d_in[0];
    const float* hidden  = (const float*)d_in[1];
    const float* command = (const float*)d_in[2];
    const float* Wq      = (const float*)d_in[3];
    const float* Wkz     = (const float*)d_in[4];
    const float* Wkh     = (const float*)d_in[5];
    const float* Wvz     = (const float*)d_in[6];
    const float* Wvh     = (const float*)d_in[7];
    const float* gammaQ  = (const float*)d_in[8];
    const float* betaQ   = (const float*)d_in[9];
    const float* gammaK  = (const float*)d_in[10];
    const float* betaK   = (const float*)d_in[11];

    char* ws = (char*)d_ws;
    __bf16* WK   = (__bf16*)(ws + WS_WK);
    __bf16* WV   = (__bf16*)(ws + WS_WV);
    float*  G    = (float*)(ws + WS_G);
    float*  CS   = (float*)(ws + WS_CS);
    float*  CMD  = (float*)(ws + WS_CMD);
    float*  Tj   = (float*)(ws + WS_T);
    float*  Uj   = (float*)(ws + WS_U);
    float*  Wq2  = (float*)(ws + WS_WQ2);
    float*  C0   = (float*)(ws + WS_C0);
    float*  outp = (float*)d_out;

    hipMemsetAsync(ws + WS_ZERO_BASE, 0, WS_ZERO_SIZE, stream);
    prep_weights<<<512, 256, 0, stream>>>(Wkz, Wkh, Wvz, Wvh, WK, WV);
    cmd_stats<<<256, 256, 0, stream>>>((const float4*)command, CMD);
    gram_kernel<<<256, 512, 0, stream>>>(feature, hidden, G, CS);
    rowstats<<<2048, 256, 0, stream>>>(Wkz, Wkh, G, CS, Tj, Uj);
    finalize_kernel<<<1, 64, 0, stream>>>(Wq, gammaQ, betaQ, gammaK, betaK,
                                          CMD, Tj, Uj, Wq2, C0);
    fused_attn<<<256, 512, 0, stream>>>(feature, hidden, (const float4*)command,
                                        WK, WV, (const float4*)Wq2, C0, outp);
}

// Round 2
// 571.446 us; speedup vs baseline: 1.1593x; 1.1593x over previous
//
#include <hip/hip_runtime.h>
#include <hip/hip_bf16.h>
#include <math.h>

// ---------------------------------------------------------------------------
// FeatureAttnNet v2 for MI355X (gfx950)
//
// Algebra: BN(K) affine per-d; additive part cancels in softmax. Further:
//   score[b,f] = Y0[b,f] + sum_c cmd[b,c]*Yc[b,f],  Y = X @ WKfold^T
// where WKfold folds BN+Wq coefficients over d (5 rows per f) -> the K-side
// GEMM shrinks 64/5x. Softmax weights precomputed -> V-loop is a clean
// double-buffered bf16 MFMA (32x32x16) pipeline, 3 blocks/CU.
// K-variance via Gram matrices (X^T X), no atomics (split-K partials).
// ---------------------------------------------------------------------------

typedef float  f32x4   __attribute__((ext_vector_type(4)));
typedef float  f32x16  __attribute__((ext_vector_type(16)));
typedef __bf16 bf16x4  __attribute__((ext_vector_type(4)));
typedef __bf16 bf16x8  __attribute__((ext_vector_type(8)));

#define MFMA16(A, B, C) __builtin_amdgcn_mfma_f32_16x16x32_bf16((A), (B), (C), 0, 0, 0)
#define MFMA32(A, B, C) __builtin_amdgcn_mfma_f32_32x32x16_bf16((A), (B), (C), 0, 0, 0)

#define EPSV 1e-5f

// swizzled 16B-chunk index within a 256B row: breaks bank conflicts for
// both the 16-row (phase1) and 32-row (phase2) fragment reads.
#define CHUNK(n, k8) ((((k8) ^ ((n) & 7)) + (((n) >> 3) << 2)) & 15)

// ---- workspace layout (bytes) ----
#define WS_WV    0x000000u   // 2048*256 bf16 = 1 MiB  [Wvz;Wvh]
#define WS_WKF   0x100000u   // 2*80*256 bf16 = 80 KiB folded K weights
#define WS_G     0x120000u   // 2*256*256 f32 = 512 KiB
#define WS_CS    0x1A0000u   // 2*256 f32 colsums (zeroed)
#define WS_CMDP  0x1A0800u   // 64*14 f32 cmd partials
#define WS_T     0x1A1800u   // 2048 f32
#define WS_U     0x1A3800u   // 2048 f32
#define WS_WQ2   0x1A5800u   // 256 f32
#define WS_C0    0x1A5C00u   // 64 f32
#define WS_GPART 0x1B0000u   // 128*65536 f32 = 32 MiB
#define WS_NEED_PARTIAL (WS_GPART + 128u * 65536u * 4u)

// ---------------------------------------------------------------------------
__global__ void prepV(const float* __restrict__ Wvz, const float* __restrict__ Wvh,
                      __bf16* __restrict__ WV)
{
    int t = blockIdx.x * 256 + threadIdx.x;     // 0..131071
    int e = t * 4;
    const float* src = (e < 262144) ? (Wvz + e) : (Wvh + (e - 262144));
    float4 a = *(const float4*)src;
    bf16x4 v = { (__bf16)a.x, (__bf16)a.y, (__bf16)a.z, (__bf16)a.w };
    *(bf16x4*)(WV + e) = v;
}

// ---------------------------------------------------------------------------
// per-block partials of colsum(cmd) + upper Gram(cmd): 64 blocks.
__global__ void cmd_stats(const float4* __restrict__ cmd, float* __restrict__ CMDP)
{
    __shared__ float sm[4][14];
    const int tid = threadIdx.x, blk = blockIdx.x;
    float v[14];
#pragma unroll
    for (int k = 0; k < 14; ++k) v[k] = 0.f;
#pragma unroll
    for (int i = 0; i < 4; ++i) {
        float4 c = cmd[blk * 1024 + i * 256 + tid];
        v[0] += c.x;  v[1] += c.y;  v[2] += c.z;  v[3] += c.w;
        v[4] += c.x*c.x; v[5] += c.x*c.y; v[6] += c.x*c.z; v[7] += c.x*c.w;
        v[8] += c.y*c.y; v[9] += c.y*c.z; v[10] += c.y*c.w;
        v[11] += c.z*c.z; v[12] += c.z*c.w; v[13] += c.w*c.w;
    }
#pragma unroll
    for (int k = 0; k < 14; ++k) {
        float s = v[k];
#pragma unroll
        for (int off = 32; off; off >>= 1) s += __shfl_xor(s, off);
        if ((tid & 63) == 0) sm[tid >> 6][k] = s;
    }
    __syncthreads();
    if (tid < 14) CMDP[blk * 14 + tid] = sm[0][tid] + sm[1][tid] + sm[2][tid] + sm[3][tid];
}

// ---------------------------------------------------------------------------
// Gram partial/atomic body. Block covers `iters*32` rows of X starting k0.
__global__ __launch_bounds__(512, 2) void gram_kernel(const float* __restrict__ feat,
        const float* __restrict__ hid, float* __restrict__ dst, float* __restrict__ CS,
        int chunk_bits, int iters, int atomic_out)
{
    __shared__ __bf16 T[256 * 40];
    const int tid  = threadIdx.x;
    const int blk  = blockIdx.x;
    const int mat  = blk >> chunk_bits;
    const int chunk = blk & ((1 << chunk_bits) - 1);
    const float* X = mat ? hid : feat;
    float* cs = CS + mat * 256;
    const int k0   = chunk * (iters * 32);
    const int wid  = tid >> 6, lane = tid & 63, quad = lane >> 4, l15 = lane & 15;
    const int c    = tid & 255;
    const int t8   = tid >> 8;

    f32x4 acc[2][16];
#pragma unroll
    for (int mt = 0; mt < 2; ++mt)
#pragma unroll
        for (int nt = 0; nt < 16; ++nt) acc[mt][nt] = (f32x4){0.f, 0.f, 0.f, 0.f};

    float clsum = 0.f;
    for (int it = 0; it < iters; ++it) {
        __syncthreads();
        const int kb = k0 + it * 32;
#pragma unroll
        for (int i = 0; i < 16; ++i) {
            int k = t8 + 2 * i;
            float x = X[(size_t)(kb + k) * 256 + c];
            clsum += x;
            T[c * 40 + k] = (__bf16)x;
        }
        __syncthreads();
        bf16x8 a0 = *(const bf16x8*)&T[(wid * 32 +      l15) * 40 + quad * 8];
        bf16x8 a1 = *(const bf16x8*)&T[(wid * 32 + 16 + l15) * 40 + quad * 8];
#pragma unroll
        for (int nt = 0; nt < 16; ++nt) {
            bf16x8 b = *(const bf16x8*)&T[(nt * 16 + l15) * 40 + quad * 8];
            acc[0][nt] = MFMA16(a0, b, acc[0][nt]);
            acc[1][nt] = MFMA16(a1, b, acc[1][nt]);
        }
    }
    atomicAdd(&cs[c], clsum);
    float* outp = atomic_out ? (dst + (size_t)mat * 65536) : (dst + (size_t)blk * 65536);
#pragma unroll
    for (int mt = 0; mt < 2; ++mt)
#pragma unroll
        for (int nt = 0; nt < 16; ++nt)
#pragma unroll
            for (int r = 0; r < 4; ++r) {
                int gi = wid * 32 + mt * 16 + quad * 4 + r;
                int gj = nt * 16 + l15;
                if (atomic_out) atomicAdd(&outp[gi * 256 + gj], acc[mt][nt][r]);
                else            outp[gi * 256 + gj] = acc[mt][nt][r];
            }
}

__global__ void gram_reduce(const float* __restrict__ Gpart, float* __restrict__ G)
{
    int idx = blockIdx.x * 256 + threadIdx.x;   // 65536 threads, 2 outputs each
#pragma unroll
    for (int h = 0; h < 2; ++h) {
        int o = idx + h * 65536;
        int mat = o >> 16, e = o & 65535;
        const float* p = Gpart + (size_t)(mat * 64) * 65536 + e;
        float s = 0.f;
        for (int cidx = 0; cidx < 64; ++cidx) s += p[(size_t)cidx * 65536];
        G[o] = s;
    }
}

// ---------------------------------------------------------------------------
// t_j = w_j^T G w_j ; u_j = w_j . colsum. Block handles 8 consecutive j.
__global__ void rowstats(const float* __restrict__ Wkz, const float* __restrict__ Wkh,
        const float* __restrict__ G, const float* __restrict__ CS,
        float* __restrict__ Tout, float* __restrict__ Uout)
{
    const int blk = blockIdx.x;               // 256 blocks
    const int mat = blk >> 7, jg = blk & 127;
    const float* Wsrc = (mat ? Wkh : Wkz) + (size_t)jg * 8 * 256;
    const float* Gm = G + (size_t)mat * 65536;
    const float* cs = CS + mat * 256;
    __shared__ float wlT[256 * 8];            // [r][jj]
    __shared__ float red[4][16];
    const int tid = threadIdx.x, wid = tid >> 6, lane = tid & 63;
#pragma unroll
    for (int jj = 0; jj < 8; ++jj) wlT[tid * 8 + jj] = Wsrc[jj * 256 + tid];
    __syncthreads();
    float inner[8];
#pragma unroll
    for (int jj = 0; jj < 8; ++jj) inner[jj] = 0.f;
    for (int r = 0; r < 256; ++r) {
        float g = Gm[r * 256 + tid];
        float4 w0 = *(const float4*)&wlT[r * 8];
        float4 w1 = *(const float4*)&wlT[r * 8 + 4];
        inner[0] = fmaf(w0.x, g, inner[0]); inner[1] = fmaf(w0.y, g, inner[1]);
        inner[2] = fmaf(w0.z, g, inner[2]); inner[3] = fmaf(w0.w, g, inner[3]);
        inner[4] = fmaf(w1.x, g, inner[4]); inner[5] = fmaf(w1.y, g, inner[5]);
        inner[6] = fmaf(w1.z, g, inner[6]); inner[7] = fmaf(w1.w, g, inner[7]);
    }
    float cst = cs[tid];
#pragma unroll
    for (int jj = 0; jj < 8; ++jj) {
        float wme = wlT[tid * 8 + jj];
        float p = wme * inner[jj];
        float u = wme * cst;
#pragma unroll
        for (int off = 32; off; off >>= 1) { p += __shfl_xor(p, off); u += __shfl_xor(u, off); }
        if (lane == 0) { red[wid][jj] = p; red[wid][jj + 8] = u; }
    }
    __syncthreads();
    if (tid < 16) {
        float s = red[0][tid] + red[1][tid] + red[2][tid] + red[3][tid];
        int jj = tid & 7;
        int j = mat * 1024 + jg * 8 + jj;
        if (tid < 8) Tout[j] = s; else Uout[j] = s;
    }
}

// ---------------------------------------------------------------------------
__global__ void finalize_kernel(const float* __restrict__ Wq,
        const float* __restrict__ gQ, const float* __restrict__ bQ,
        const float* __restrict__ gK, const float* __restrict__ bK,
        const float* __restrict__ CMDP, const float* __restrict__ T,
        const float* __restrict__ U, float* __restrict__ Wq2, float* __restrict__ C0)
{
    __shared__ float s14[14];
    const int d = threadIdx.x;
    if (d < 14) {
        float s = 0.f;
        for (int b = 0; b < 64; ++b) s += CMDP[b * 14 + d];
        s14[d] = s;
    }
    __syncthreads();
    float s4[4] = { s14[0], s14[1], s14[2], s14[3] };
    float gc[4][4];
    gc[0][0] = s14[4];
    gc[0][1] = gc[1][0] = s14[5];
    gc[0][2] = gc[2][0] = s14[6];
    gc[0][3] = gc[3][0] = s14[7];
    gc[1][1] = s14[8];
    gc[1][2] = gc[2][1] = s14[9];
    gc[1][3] = gc[3][1] = s14[10];
    gc[2][2] = s14[11];
    gc[2][3] = gc[3][2] = s14[12];
    gc[3][3] = s14[13];
    float wq[4];
#pragma unroll
    for (int c = 0; c < 4; ++c) wq[c] = Wq[d * 4 + c];
    const float invB = 1.0f / 65536.0f;
    float mQ = (wq[0]*s4[0] + wq[1]*s4[1] + wq[2]*s4[2] + wq[3]*s4[3]) * invB;
    float eq2 = 0.f;
#pragma unroll
    for (int c = 0; c < 4; ++c)
#pragma unroll
        for (int c2 = 0; c2 < 4; ++c2) eq2 += wq[c] * wq[c2] * gc[c][c2];
    eq2 *= invB;
    float vQ  = eq2 - mQ * mQ;
    float aQ  = gQ[d] / sqrtf(vQ + EPSV);
    float bQv = bQ[d] - mQ * aQ;
    float S2 = 0.f, S1 = 0.f;
#pragma unroll
    for (int f = 0; f < 32; ++f) { S2 += T[f * 64 + d]; S1 += U[f * 64 + d]; }
    const float invBF = 1.0f / (65536.0f * 32.0f);
    float e2 = S2 * invBF, mK = S1 * invBF;
    float vK = e2 - mK * mK;
    float aK = gK[d] / sqrtf(vK + EPSV);
    float c1 = aQ * aK * 0.125f;      // 1/sqrt(64) folded in
    C0[d] = bQv * aK * 0.125f;
#pragma unroll
    for (int c = 0; c < 4; ++c) Wq2[d * 4 + c] = c1 * wq[c];
}

// ---------------------------------------------------------------------------
// WKfold[h][r = c*16 + fl][k] = sum_d coef_c[d] * W_h[fl*64+d][k], bf16 out.
__global__ void foldK(const float* __restrict__ Wkz, const float* __restrict__ Wkh,
                      const float* __restrict__ Wq2, const float* __restrict__ C0,
                      __bf16* __restrict__ WKF)
{
    const int blk = blockIdx.x;               // 160
    const int h = blk / 80, r = blk % 80;
    const int c = r >> 4, fl = r & 15;
    const float* Wsrc = (h ? Wkh : Wkz) + (size_t)fl * 64 * 256;
    const int k = threadIdx.x;
    float s = 0.f;
    for (int d = 0; d < 64; ++d) {
        float coef = (c == 0) ? C0[d] : Wq2[d * 4 + (c - 1)];
        s = fmaf(coef, Wsrc[d * 256 + k], s);
    }
    WKF[(size_t)(h * 80 + r) * 256 + k] = (__bf16)s;
}

// ---------------------------------------------------------------------------
// Fused attention: 256 blocks x 256 threads (4 waves), 256 rows/block.
// LDS: dbuf 2x16KB weight tiles + bf16 wgt[33][256] = 49664 B -> 3 blocks/CU.
__global__ __launch_bounds__(256) void fused_attn(
        const float* __restrict__ feat, const float* __restrict__ hid,
        const float4* __restrict__ cmd, const __bf16* __restrict__ WV,
        const __bf16* __restrict__ WKF, float* __restrict__ out)
{
    __shared__ __align__(16) char smem[49664];
    const int tid  = threadIdx.x;
    const int wid  = tid >> 6, lane = tid & 63;
    const int quad = lane >> 4, l15 = lane & 15;
    const int l5   = lane & 31, hi = lane >> 5;
    const int b0   = blockIdx.x << 8;
    const int wavebase = wid << 6;            // 64 rows per wave

    // ---------------- phase 1: scores -> softmax weights ----------------
    float lacc[16];
#pragma unroll
    for (int i = 0; i < 16; ++i) lacc[i] = 0.f;

    for (int h = 0; h < 2; ++h) {
        const float* Xh = h ? hid : feat;
        f32x4 acc1[4][5];
#pragma unroll
        for (int mt = 0; mt < 4; ++mt)
#pragma unroll
            for (int nt = 0; nt < 5; ++nt) acc1[mt][nt] = (f32x4){0.f, 0.f, 0.f, 0.f};

        for (int s = 0; s < 2; ++s) {
            __syncthreads();
            // stage WKfold sub-tile: 80 rows x 128 k
#pragma unroll
            for (int i = 0; i < 5; ++i) {
                int cc = tid + i * 256;
                int n = cc >> 4, k8 = cc & 15;
                bf16x8 v = *(const bf16x8*)(WKF + (size_t)(h * 80 + n) * 256 + s * 128 + k8 * 8);
                *(bf16x8*)(smem + n * 256 + (CHUNK(n, k8) << 4)) = v;
            }
            __syncthreads();
            // A fragments (16x16x32): m=l15, k=quad*8+j
            bf16x8 a1[4][4];
#pragma unroll
            for (int mt = 0; mt < 4; ++mt)
#pragma unroll
                for (int ks = 0; ks < 4; ++ks) {
                    const float* p = Xh + ((size_t)(b0 + wavebase + mt * 16 + l15) << 8)
                                        + s * 128 + ks * 32 + quad * 8;
                    float4 x0 = *(const float4*)p;
                    float4 x1 = *(const float4*)(p + 4);
                    a1[mt][ks] = (bf16x8){ (__bf16)x0.x, (__bf16)x0.y, (__bf16)x0.z, (__bf16)x0.w,
                                           (__bf16)x1.x, (__bf16)x1.y, (__bf16)x1.z, (__bf16)x1.w };
                }
#pragma unroll
            for (int ks = 0; ks < 4; ++ks)
#pragma unroll
                for (int nt = 0; nt < 5; ++nt) {
                    int n = nt * 16 + l15;
                    bf16x8 bfr = *(const bf16x8*)(smem + n * 256 + (CHUNK(n, ks * 4 + quad) << 4));
#pragma unroll
                    for (int mt = 0; mt < 4; ++mt)
                        acc1[mt][nt] = MFMA16(a1[mt][ks], bfr, acc1[mt][nt]);
                }
        }
        // epilogue: score -> exp -> wgt (bf16, LDS [f][row]); accumulate l
#pragma unroll
        for (int mt = 0; mt < 4; ++mt) {
            bf16x4 wv4;
#pragma unroll
            for (int r = 0; r < 4; ++r) {
                float4 cm = cmd[b0 + wavebase + mt * 16 + quad * 4 + r];
                float sc = acc1[mt][0][r] + cm.x * acc1[mt][1][r] + cm.y * acc1[mt][2][r]
                                          + cm.z * acc1[mt][3][r] + cm.w * acc1[mt][4][r];
                float w = __expf(sc);
                wv4[r] = (__bf16)w;
                float ws = w;
                ws += __shfl_xor(ws, 1); ws += __shfl_xor(ws, 2);
                ws += __shfl_xor(ws, 4); ws += __shfl_xor(ws, 8);
                lacc[mt * 4 + r] += ws;
            }
            *(bf16x4*)(smem + 32768 +
                (((h * 16 + l15) * 256 + wavebase + mt * 16 + quad * 4) << 1)) = wv4;
        }
    }
    // store l (row f-slot 32) — one lane per quad
    if (l15 == 0) {
#pragma unroll
        for (int mt = 0; mt < 4; ++mt) {
            bf16x4 lv = { (__bf16)lacc[mt * 4 + 0], (__bf16)lacc[mt * 4 + 1],
                          (__bf16)lacc[mt * 4 + 2], (__bf16)lacc[mt * 4 + 3] };
            *(bf16x4*)(smem + 32768 +
                ((32 * 256 + wavebase + mt * 16 + quad * 4) << 1)) = lv;
        }
    }

    // ---------------- phase 2: weighted V accumulation ----------------
    f32x16 s_acc[2][2];
#pragma unroll
    for (int mt = 0; mt < 2; ++mt)
#pragma unroll
        for (int nt = 0; nt < 2; ++nt)
#pragma unroll
            for (int r = 0; r < 16; ++r) s_acc[mt][nt][r] = 0.f;

    for (int h = 0; h < 2; ++h) {
        const float* Xh = h ? hid : feat;
        // A fragments (32x32x16): m=l5, k=hi*8+j; u indexes 16-wide k chunks
        bf16x8 a2[2][16];
#pragma unroll
        for (int mt = 0; mt < 2; ++mt)
#pragma unroll
            for (int u = 0; u < 16; ++u) {
                const float* p = Xh + ((size_t)(b0 + wavebase + mt * 32 + l5) << 8)
                                    + u * 16 + hi * 8;
                float4 x0 = *(const float4*)p;
                float4 x1 = *(const float4*)(p + 4);
                a2[mt][u] = (bf16x8){ (__bf16)x0.x, (__bf16)x0.y, (__bf16)x0.z, (__bf16)x0.w,
                                      (__bf16)x1.x, (__bf16)x1.y, (__bf16)x1.z, (__bf16)x1.w };
            }
        // preload sub-tile 0
        bf16x8 st[4];
        {
            const __bf16* base = WV + ((size_t)(h * 16) << 14);  // f=0, s=0
#pragma unroll
            for (int i = 0; i < 4; ++i) {
                int cc = tid + i * 256;
                int n = cc >> 4, k8 = cc & 15;
                st[i] = *(const bf16x8*)(base + (size_t)n * 256 + k8 * 8);
            }
        }
        __syncthreads();
        f32x16 acc2[2][2];
        for (int t = 0; t < 32; ++t) {
            char* buf = smem + (t & 1) * 16384;
#pragma unroll
            for (int i = 0; i < 4; ++i) {
                int cc = tid + i * 256;
                int n = cc >> 4, k8 = cc & 15;
                *(bf16x8*)(buf + n * 256 + (CHUNK(n, k8) << 4)) = st[i];
            }
            __syncthreads();
            if (t < 31) {
                int tn = t + 1, fn = tn >> 1, sn = tn & 1;
                const __bf16* base = WV + ((size_t)((h * 16 + fn) * 64) << 8) + sn * 128;
#pragma unroll
                for (int i = 0; i < 4; ++i) {
                    int cc = tid + i * 256;
                    int n = cc >> 4, k8 = cc & 15;
                    st[i] = *(const bf16x8*)(base + (size_t)n * 256 + k8 * 8);
                }
            }
            const int s = t & 1;
            if (!s) {
#pragma unroll
                for (int mt = 0; mt < 2; ++mt)
#pragma unroll
                    for (int nt = 0; nt < 2; ++nt)
#pragma unroll
                        for (int r = 0; r < 16; ++r) acc2[mt][nt][r] = 0.f;
            }
#pragma unroll
            for (int ks = 0; ks < 8; ++ks)
#pragma unroll
                for (int nt = 0; nt < 2; ++nt) {
                    int n = nt * 32 + l5;
                    bf16x8 bfr = *(const bf16x8*)(buf + n * 256 + (CHUNK(n, ks * 2 + hi) << 4));
#pragma unroll
                    for (int mt = 0; mt < 2; ++mt)
                        acc2[mt][nt] = MFMA32(a2[mt][s * 8 + ks], bfr, acc2[mt][nt]);
                }
            if (s) {
                const int fg = h * 16 + (t >> 1);
#pragma unroll
                for (int mt = 0; mt < 2; ++mt)
#pragma unroll
                    for (int g = 0; g < 4; ++g) {
                        bf16x4 wv = *(const bf16x4*)(smem + 32768 +
                            ((fg * 256 + wavebase + mt * 32 + g * 8 + hi * 4) << 1));
#pragma unroll
                        for (int j = 0; j < 4; ++j) {
                            float w = (float)wv[j];
                            s_acc[mt][0][g * 4 + j] += w * acc2[mt][0][g * 4 + j];
                            s_acc[mt][1][g * 4 + j] += w * acc2[mt][1][g * 4 + j];
                        }
                    }
            }
        }
    }

    // ---------------- epilogue: divide by l, store ----------------
#pragma unroll
    for (int mt = 0; mt < 2; ++mt)
#pragma unroll
        for (int g = 0; g < 4; ++g) {
            bf16x4 lv = *(const bf16x4*)(smem + 32768 +
                ((32 * 256 + wavebase + mt * 32 + g * 8 + hi * 4) << 1));
#pragma unroll
            for (int j = 0; j < 4; ++j) {
                float linv = 1.0f / (float)lv[j];
                int row = wavebase + mt * 32 + g * 8 + hi * 4 + j;
                out[((size_t)(b0 + row) << 6) + 0 * 32 + l5]  = s_acc[mt][0][g * 4 + j] * linv;
                out[((size_t)(b0 + row) << 6) + 1 * 32 + l5]  = s_acc[mt][1][g * 4 + j] * linv;
            }
        }
}

// ---------------------------------------------------------------------------
extern "C" void kernel_launch(void* const* d_in, const int* in_sizes, int n_in,
                              void* d_out, int out_size, void* d_ws, size_t ws_size,
                              hipStream_t stream)
{
    (void)in_sizes; (void)n_in; (void)out_size;
    const float* feature = (const float*)d_in[0];
    const float* hidden  = (const float*)d_in[1];
    const float* command = (const float*)d_in[2];
    const float* Wq      = (const float*)d_in[3];
    const float* Wkz     = (const float*)d_in[4];
    const float* Wkh     = (const float*)d_in[5];
    const float* Wvz     = (const float*)d_in[6];
    const float* Wvh     = (const float*)d_in[7];
    const float* gammaQ  = (const float*)d_in[8];
    const float* betaQ   = (const float*)d_in[9];
    const float* gammaK  = (const float*)d_in[10];
    const float* betaK   = (const float*)d_in[11];

    char* ws = (char*)d_ws;
    __bf16* WV   = (__bf16*)(ws + WS_WV);
    __bf16* WKF  = (__bf16*)(ws + WS_WKF);
    float*  G    = (float*)(ws + WS_G);
    float*  CS   = (float*)(ws + WS_CS);
    float*  CMDP = (float*)(ws + WS_CMDP);
    float*  Tj   = (float*)(ws + WS_T);
    float*  Uj   = (float*)(ws + WS_U);
    float*  Wq2  = (float*)(ws + WS_WQ2);
    float*  C0   = (float*)(ws + WS_C0);
    float*  Gp   = (float*)(ws + WS_GPART);
    float*  outp = (float*)d_out;

    const bool partial = ws_size >= (size_t)WS_NEED_PARTIAL;

    hipMemsetAsync(ws + WS_CS, 0, 0x800, stream);
    if (!partial) hipMemsetAsync(ws + WS_G, 0, 0x80000, stream);

    prepV<<<512, 256, 0, stream>>>(Wvz, Wvh, WV);
    cmd_stats<<<64, 256, 0, stream>>>((const float4*)command, CMDP);
    if (partial) {
        gram_kernel<<<128, 512, 0, stream>>>(feature, hidden, Gp, CS, 6, 32, 0);
        gram_reduce<<<256, 256, 0, stream>>>(Gp, G);
    } else {
        gram_kernel<<<256, 512, 0, stream>>>(feature, hidden, G, CS, 7, 16, 1);
    }
    rowstats<<<256, 256, 0, stream>>>(Wkz, Wkh, G, CS, Tj, Uj);
    finalize_kernel<<<1, 64, 0, stream>>>(Wq, gammaQ, betaQ, gammaK, betaK,
                                          CMDP, Tj, Uj, Wq2, C0);
    foldK<<<160, 256, 0, stream>>>(Wkz, Wkh, Wq2, C0, WKF);
    fused_attn<<<256, 256, 0, stream>>>(feature, hidden, (const float4*)command,
                                        WV, WKF, outp);
}